// Round 8
// baseline (571.143 us; speedup 1.0000x reference)
//
#include <hip/hip_runtime.h>

typedef __attribute__((ext_vector_type(8))) short short8;
typedef __attribute__((ext_vector_type(4))) float f32x4;
typedef __attribute__((ext_vector_type(4))) unsigned short u16x4;
typedef unsigned short u16;

#define D_DIM 1024
#define NKT 32  // K / 32, all 4 planes fused per K-slice

__device__ __forceinline__ u16 f2bf(float f) {
  unsigned u = __builtin_bit_cast(unsigned, f);
  u += 0x7fffu + ((u >> 16) & 1u);
  return (u16)(u >> 16);
}
__device__ __forceinline__ float bf2f(u16 b) {
  return __builtin_bit_cast(float, ((unsigned)b) << 16);
}
__device__ __forceinline__ float gelu_f(float x) {
  float i = 0.7978845608028654f * (x + 0.044715f * x * x * x);
  float ex = __builtin_amdgcn_exp2f(i * 2.885390081777927f);  // e^{2i}
  float th = 1.0f - 2.0f * __builtin_amdgcn_rcpf(ex + 1.0f);
  return 0.5f * x * (1.0f + th);
}
__device__ __forceinline__ f32x4 mfma16(short8 a, short8 b, f32x4 c) {
  return __builtin_amdgcn_mfma_f32_16x16x32_bf16(a, b, c, 0, 0, 0);
}
__device__ __forceinline__ void glds16(const u16* g, const u16* l) {
  __builtin_amdgcn_global_load_lds(
      (const __attribute__((address_space(1))) void*)g,
      (__attribute__((address_space(3))) void*)l, 16, 0, 0);
}

// ---------------- prep kernels ----------------
__global__ __launch_bounds__(256) void prep_w_kernel(
    const float* __restrict__ W, u16* __restrict__ Wth, u16* __restrict__ Wtl) {
  __shared__ float tile[64][65];
  const int t = threadIdx.x;
  const int k0 = blockIdx.x * 64, n0 = blockIdx.y * 64;
  const size_t lbase = (size_t)blockIdx.z * D_DIM * D_DIM;
#pragma unroll
  for (int j = 0; j < 16; ++j) {
    int idx = t + 256 * j;
    int r = idx >> 6, c = idx & 63;
    tile[r][c] = W[lbase + (size_t)(k0 + r) * D_DIM + (n0 + c)];
  }
  __syncthreads();
#pragma unroll
  for (int j = 0; j < 16; ++j) {
    int idx = t + 256 * j;
    int r = idx >> 6, c = idx & 63;
    float f = tile[c][r];
    u16 hb = f2bf(f);
    u16 lb = f2bf(f - bf2f(hb));
    size_t oidx = lbase + (size_t)(n0 + r) * D_DIM + (k0 + c);
    Wth[oidx] = hb;
    Wtl[oidx] = lb;
  }
}

__global__ __launch_bounds__(256) void prep_x_kernel(
    const float* __restrict__ x, u16* __restrict__ xh, u16* __restrict__ xl) {
  size_t i = ((size_t)blockIdx.x * 256 + threadIdx.x) * 4;
  const float4 v = *(const float4*)(x + i);
  const float fv[4] = {v.x, v.y, v.z, v.w};
  u16x4 h4, l4;
#pragma unroll
  for (int c = 0; c < 4; ++c) {
    u16 hb = f2bf(fv[c]);
    h4[c] = hb;
    l4[c] = f2bf(fv[c] - bf2f(hb));
  }
  *(u16x4*)(xh + i) = h4;
  *(u16x4*)(xl + i) = l4;
}

// ---------------- 256x256 6-phase GEMM + ACT epilogue ----------
// LDS per buffer (32768 u16): Ah[256][32] | Al | Bh | Bl, each 8192 u16.
// Within a plane, 16B slot s of row r holds global k-chunk s ^ ((r>>1)&3).
// Per K-tile: 6 phases, each {ds_read cluster + glds -> s_barrier ->
// lgkmcnt(0) -> setprio(1) 16 MFMA setprio(0) -> s_barrier}. The barrier
// pairs keep the LDS pipe (reads of later waves) and the MFMA pipe (early
// waves) concurrently loaded (m201/m218 mechanism). One vmcnt(0) seal per
// tile in P5; the loads it drains were issued 4 phases earlier.
__global__ __launch_bounds__(512, 2) void gemm_act_kernel(
    const u16* __restrict__ Ahp, const u16* __restrict__ Alp,
    const u16* __restrict__ Bhp, const u16* __restrict__ Blp,
    const float* __restrict__ bias, const float* __restrict__ halt_w,
    u16* __restrict__ Hh, u16* __restrict__ Hl, float* __restrict__ zpart,
    int M, int writeLo) {
  extern __shared__ u16 lds[];  // 2 x 64 KiB
  const int t = threadIdx.x;
  const int bid = blockIdx.x;                  // 256 blocks
  const int wg = (bid & 7) * 32 + (bid >> 3);  // XCD-chunked, bijective
  const int bn0 = (wg & 3) * 256;
  const int bm0 = (wg >> 2) * 256;
  const int lane = t & 63, wid = t >> 6;
  const int wr = wid >> 2, wc = wid & 3;
  const int g = lane >> 4, r16 = lane & 15;

  // staging geometry: unit j of wave = 1024B = 16 rows x 64B of one plane
  const int lrow = lane >> 2;                         // row within 16-row unit
  const int lchunk = (lane & 3) ^ ((lane >> 3) & 3);  // global k-chunk
  const u16* sbase[8];
  int ldsoff[8];
#pragma unroll
  for (int j = 0; j < 8; ++j) {
    const int p = j >> 1;             // plane: 0 Ah, 1 Al, 2 Bh, 3 Bl
    const int v = wid + 8 * (j & 1);  // 16-row group 0..15
    const u16* gp = (p == 0) ? Ahp : (p == 1) ? Alp : (p == 2) ? Bhp : Blp;
    const int r0 = (p < 2) ? bm0 : bn0;
    sbase[j] = gp + (size_t)(r0 + 16 * v + lrow) * D_DIM + lchunk * 8;
    ldsoff[j] = p * 8192 + v * 512 + lane * 8;
  }

  // fragment read offsets (u16): row*32 + (g ^ ((r16>>1)&3))*8
  const int fsw = ((g ^ (r16 >> 1)) & 3) * 8;
  const int arow0 = (wr * 128 + r16) * 32 + fsw;
  const int brow0 = 16384 + (wc * 64 + r16) * 32 + fsw;

  f32x4 acc[8][4];
#pragma unroll
  for (int i = 0; i < 8; ++i)
#pragma unroll
    for (int j = 0; j < 4; ++j) acc[i][j] = (f32x4)0.0f;

#define SB() __builtin_amdgcn_sched_barrier(0)
#define GATE()                                         \
  SB();                                                \
  __builtin_amdgcn_s_barrier();                        \
  asm volatile("s_waitcnt lgkmcnt(0)" ::: "memory");   \
  SB();                                                \
  __builtin_amdgcn_s_setprio(1)
#define CLOSE()                \
  __builtin_amdgcn_s_setprio(0); \
  SB();                          \
  __builtin_amdgcn_s_barrier();  \
  SB()
#define RD4(DST, BASE)                                                 \
  _Pragma("unroll") for (int i_ = 0; i_ < 4; ++i_) DST[i_] =           \
      *(const short8*)((BASE) + i_ * 512)
#define MFMA16(AF, BF, O)                                              \
  _Pragma("unroll") for (int i_ = 0; i_ < 4; ++i_)                     \
      _Pragma("unroll") for (int n_ = 0; n_ < 4; ++n_) acc[(O) + i_][n_] = \
          mfma16(AF[i_], BF[n_], acc[(O) + i_][n_])

  // prologue: stage tile 0 fully into buf 0
#pragma unroll
  for (int j = 0; j < 8; ++j) glds16(sbase[j], lds + ldsoff[j]);
  asm volatile("s_waitcnt vmcnt(0)" ::: "memory");
  __builtin_amdgcn_s_barrier();

#pragma unroll 1
  for (int kt = 0; kt < NKT; ++kt) {
    const u16* Lb = lds + ((kt & 1) << 15);
    const int ktn = (kt + 1 < NKT) ? (kt + 1) : kt;  // clamp: last tile
    const int k0n = ktn << 5;
    u16* db = lds + (((kt & 1) ^ 1) << 15);
    short8 ah[4], al[4], ah2[4], al2[4], bh[4], bl[4];

    // P0: read ah,bh; stage next Ah,Al
    RD4(ah, Lb + arow0);
    RD4(bh, Lb + brow0);
    glds16(sbase[0] + k0n, db + ldsoff[0]);
    glds16(sbase[1] + k0n, db + ldsoff[1]);
    glds16(sbase[2] + k0n, db + ldsoff[2]);
    glds16(sbase[3] + k0n, db + ldsoff[3]);
    GATE();
    MFMA16(ah, bh, 0);
    CLOSE();
    // P1: read bl; stage next Bh,Bl
    RD4(bl, Lb + 8192 + brow0);
    glds16(sbase[4] + k0n, db + ldsoff[4]);
    glds16(sbase[5] + k0n, db + ldsoff[5]);
    glds16(sbase[6] + k0n, db + ldsoff[6]);
    glds16(sbase[7] + k0n, db + ldsoff[7]);
    GATE();
    MFMA16(ah, bl, 0);
    CLOSE();
    // P2: read al
    RD4(al, Lb + 8192 + arow0);
    GATE();
    MFMA16(al, bh, 0);
    CLOSE();
    // P3: read ah2
    RD4(ah2, Lb + arow0 + 2048);
    GATE();
    MFMA16(ah2, bh, 4);
    CLOSE();
    // P4: read al2
    RD4(al2, Lb + 8192 + arow0 + 2048);
    GATE();
    MFMA16(ah2, bl, 4);
    CLOSE();
    // P5: seal (loads drained were issued 4 phases ago) + final cluster
    asm volatile("s_waitcnt vmcnt(0)" ::: "memory");
    GATE();
    MFMA16(al2, bh, 4);
    CLOSE();
  }
#undef SB
#undef GATE
#undef CLOSE
#undef RD4
#undef MFMA16

  __syncthreads();  // K-loop retired; LDS free for epilogue reuse

  // ---- epilogue: bias + gelu (in place), halt partial dot
  float bv[4], hwv[4];
#pragma unroll
  for (int ni = 0; ni < 4; ++ni) {
    int col = bn0 + wc * 64 + ni * 16 + r16;
    bv[ni] = bias[col];
    hwv[ni] = halt_w[col];
  }
  float zp[8][4];
#pragma unroll
  for (int mi = 0; mi < 8; ++mi)
#pragma unroll
    for (int j = 0; j < 4; ++j) {
      float zz = 0.0f;
#pragma unroll
      for (int ni = 0; ni < 4; ++ni) {
        float v = gelu_f(acc[mi][ni][j] + bv[ni]);
        acc[mi][ni][j] = v;
        zz += v * hwv[ni];
      }
      zp[mi][j] = zz;
    }
#pragma unroll
  for (int off = 1; off < 16; off <<= 1)
#pragma unroll
    for (int mi = 0; mi < 8; ++mi)
#pragma unroll
      for (int j = 0; j < 4; ++j) zp[mi][j] += __shfl_xor(zp[mi][j], off);
  float* zf = (float*)lds;  // [4][256]
  if (r16 == 0) {
#pragma unroll
    for (int mi = 0; mi < 8; ++mi)
#pragma unroll
      for (int j = 0; j < 4; ++j)
        zf[wc * 256 + wr * 128 + mi * 16 + g * 4 + j] = zp[mi][j];
  }
  __syncthreads();
  if (t < 256) {
    float z = zf[t] + zf[256 + t] + zf[512 + t] + zf[768 + t];
    zpart[(size_t)(bn0 >> 8) * M + bm0 + t] = z;
  }
  __syncthreads();

  // ---- hi plane repack + store
  u16* hp = lds;  // [256][256]
#pragma unroll
  for (int mi = 0; mi < 8; ++mi)
#pragma unroll
    for (int ni = 0; ni < 4; ++ni)
#pragma unroll
      for (int j = 0; j < 4; ++j)
        hp[(wr * 128 + mi * 16 + g * 4 + j) * 256 + wc * 64 + ni * 16 + r16] =
            f2bf(acc[mi][ni][j]);
  __syncthreads();
#pragma unroll
  for (int q = 0; q < 16; ++q) {
    int idx = q * 512 + t;
    int r = idx >> 5, cc = idx & 31;
    *(short8*)(Hh + (size_t)(bm0 + r) * D_DIM + bn0 + cc * 8) =
        *(const short8*)&hp[r * 256 + cc * 8];
  }
  // ---- lo plane (skipped for the last layer: never consumed)
  if (writeLo) {
    __syncthreads();
#pragma unroll
    for (int mi = 0; mi < 8; ++mi)
#pragma unroll
      for (int ni = 0; ni < 4; ++ni)
#pragma unroll
        for (int j = 0; j < 4; ++j) {
          float v = acc[mi][ni][j];
          hp[(wr * 128 + mi * 16 + g * 4 + j) * 256 + wc * 64 + ni * 16 +
             r16] = f2bf(v - bf2f(f2bf(v)));
        }
    __syncthreads();
#pragma unroll
    for (int q = 0; q < 16; ++q) {
      int idx = q * 512 + t;
      int r = idx >> 5, cc = idx & 31;
      *(short8*)(Hl + (size_t)(bm0 + r) * D_DIM + bn0 + cc * 8) =
          *(const short8*)&hp[r * 256 + cc * 8];
    }
  }
}

// ---------------- ACT scalar kernels ----------------
__global__ __launch_bounds__(256) void act_weights_kernel(
    const float* __restrict__ zpart, const float* __restrict__ halt_b,
    float* __restrict__ cum, float* __restrict__ rem, float* __restrict__ pond,
    float* __restrict__ wout, int step, int last, int M, int nblk) {
  int tok = blockIdx.x * 256 + threadIdx.x;
  float z = halt_b[0];
  for (int nb = 0; nb < nblk; ++nb) z += zpart[(size_t)nb * M + tok];
  float p = 1.0f / (1.0f + expf(-z));
  float c, r, q;
  if (step == 0) {
    c = 0.0f; r = 1.0f; q = 0.0f;
  } else {
    c = cum[tok]; r = rem[tok]; q = pond[tok];
  }
  float weight = last ? r : (((c + p) >= 0.99f) ? r : p);
  q += weight;
  c += weight;
  r = fmaxf(1.0f - c, 0.0f);
  cum[tok] = c;
  rem[tok] = r;
  pond[tok] = q;
  wout[tok] = weight;
}

// out (+)= sum_s w_s * h_s   (hi plane only: bf16 precision ample for output)
__global__ __launch_bounds__(256) void act_out_kernel(
    const u16* __restrict__ hbase, size_t pstride, const float* __restrict__ w,
    int nsteps, int accum, float* __restrict__ out, int M) {
  size_t gid = (size_t)blockIdx.x * 256 + threadIdx.x;
  int tok = (int)(gid >> 7);
  int off = ((int)gid & 127) * 8;
  size_t base = (size_t)tok * D_DIM + off;
  float o[8];
  if (accum) {
    float4 a = *(const float4*)(out + base);
    float4 b = *(const float4*)(out + base + 4);
    o[0] = a.x; o[1] = a.y; o[2] = a.z; o[3] = a.w;
    o[4] = b.x; o[5] = b.y; o[6] = b.z; o[7] = b.w;
  } else {
#pragma unroll
    for (int j = 0; j < 8; ++j) o[j] = 0.0f;
  }
  for (int s = 0; s < nsteps; ++s) {
    float ws = w[(size_t)s * M + tok];
    short8 hi = *(const short8*)(hbase + (size_t)s * pstride + base);
#pragma unroll
    for (int j = 0; j < 8; ++j) o[j] += ws * bf2f((u16)hi[j]);
  }
  *(float4*)(out + base) = make_float4(o[0], o[1], o[2], o[3]);
  *(float4*)(out + base + 4) = make_float4(o[4], o[5], o[6], o[7]);
}

__global__ __launch_bounds__(256) void ponder_reduce_kernel(
    const float* __restrict__ pond, float* __restrict__ o, int n) {
  __shared__ float sh[256];
  float a = 0.0f;
  for (int i = threadIdx.x; i < n; i += 256) a += pond[i];
  sh[threadIdx.x] = a;
  __syncthreads();
  for (int s = 128; s; s >>= 1) {
    if ((int)threadIdx.x < s) sh[threadIdx.x] += sh[threadIdx.x + s];
    __syncthreads();
  }
  if (threadIdx.x == 0) o[0] = sh[0] / (float)n;
}

extern "C" void kernel_launch(void* const* d_in, const int* in_sizes, int n_in,
                              void* d_out, int out_size, void* d_ws,
                              size_t ws_size, hipStream_t stream) {
  const float* x = (const float*)d_in[0];
  const float* layer_w = (const float*)d_in[1];
  const float* layer_b = (const float*)d_in[2];
  const float* halt_w = (const float*)d_in[3];
  const float* halt_b = (const float*)d_in[4];
  float* out = (float*)d_out;

  const int D = D_DIM;
  const int M = in_sizes[0] / D;        // 16384
  const int L = in_sizes[1] / (D * D);  // 4
  const size_t MD = (size_t)M * D, DD = (size_t)D * D;

  char* ws = (char*)d_ws;
  size_t off = 0;
  auto alloc = [&](size_t bytes) {
    void* p = ws + off;
    off += (bytes + 255) & ~(size_t)255;
    return p;
  };
  u16* Wsplit = (u16*)alloc((size_t)L * 2 * DD * sizeof(u16));  // hi | lo
  float* zpart = (float*)alloc(4 * (size_t)M * 4);
  float* wbuf = (float*)alloc((size_t)L * M * 4);
  float* cum = (float*)alloc((size_t)M * 4);
  float* rem = (float*)alloc((size_t)M * 4);
  float* pond = (float*)alloc((size_t)M * 4);

  const size_t planeElems = 2 * MD;          // hi + lo (u16)
  const size_t planeBytes = planeElems * 2;  // 67.1 MB
  const bool deferred = (off + (size_t)(L + 1) * planeBytes) <= ws_size;
  const int nbufs = deferred ? (L + 1) : 2;
  u16* planes = (u16*)alloc((size_t)nbufs * planeBytes);

  hipFuncSetAttribute((const void*)gemm_act_kernel,
                      hipFuncAttributeMaxDynamicSharedMemorySize, 131072);

  prep_x_kernel<<<(unsigned)(MD / 1024), 256, 0, stream>>>(x, planes,
                                                           planes + MD);
  prep_w_kernel<<<dim3(D / 64, D / 64, L), 256, 0, stream>>>(
      layer_w, Wsplit, Wsplit + (size_t)L * DD);

  for (int s = 0; s < L; ++s) {
    u16* pin = planes + (size_t)(deferred ? s : (s & 1)) * planeElems;
    u16* pout =
        planes + (size_t)(deferred ? (s + 1) : ((s + 1) & 1)) * planeElems;
    gemm_act_kernel<<<dim3(M / 256 * (D / 256)), 512, 131072, stream>>>(
        pin, pin + MD, Wsplit + (size_t)s * DD, Wsplit + (size_t)(L + s) * DD,
        layer_b + (size_t)s * D, halt_w, pout, pout + MD, zpart, M,
        (s < L - 1) ? 1 : 0);
    act_weights_kernel<<<M / 256, 256, 0, stream>>>(
        zpart, halt_b, cum, rem, pond, wbuf + (size_t)s * M, s,
        (s == L - 1) ? 1 : 0, M, D / 256);
    if (!deferred)
      act_out_kernel<<<(unsigned)(MD / 2048), 256, 0, stream>>>(
          pout, 0, wbuf + (size_t)s * M, 1, (s > 0) ? 1 : 0, out, M);
  }
  if (deferred)
    act_out_kernel<<<(unsigned)(MD / 2048), 256, 0, stream>>>(
        planes + planeElems, planeElems, wbuf, L, 0, out, M);
  ponder_reduce_kernel<<<1, 256, 0, stream>>>(pond, out + MD, M);
}